// Round 1
// baseline (167.920 us; speedup 1.0000x reference)
//
#include <hip/hip_runtime.h>

// GIoU loss, N=4M boxes. Memory-bound: 128 MB read / launch.
// Box layout [N,4] -> one float4 per box, fully coalesced.

__global__ void giou_zero_kernel(double* acc) {
    if (threadIdx.x == 0 && blockIdx.x == 0) *acc = 0.0;
}

__global__ __launch_bounds__(256) void giou_main_kernel(
        const float4* __restrict__ pred,
        const float4* __restrict__ targ,
        double* __restrict__ acc,
        int n) {
    float sum = 0.0f;
    int stride = gridDim.x * blockDim.x;
    for (int i = blockIdx.x * blockDim.x + threadIdx.x; i < n; i += stride) {
        float4 p = pred[i];
        float4 t = targ[i];
        float area_p = (p.z - p.x) * (p.w - p.y);
        float area_t = (t.z - t.x) * (t.w - t.y);
        float iw = fmaxf(fminf(p.z, t.z) - fmaxf(p.x, t.x), 0.0f);
        float ih = fmaxf(fminf(p.w, t.w) - fmaxf(p.y, t.y), 0.0f);
        float inter = iw * ih;
        float uni   = area_p + area_t - inter;
        float iou   = inter / uni;
        float cw = fmaxf(p.z, t.z) - fminf(p.x, t.x);
        float ch = fmaxf(p.w, t.w) - fminf(p.y, t.y);
        float area_c = cw * ch;
        float giou = iou - (area_c - uni) / area_c;
        sum += 1.0f - giou;
    }
    // wave-level butterfly reduce (wave = 64 on CDNA)
    #pragma unroll
    for (int off = 32; off > 0; off >>= 1)
        sum += __shfl_down(sum, off, 64);

    __shared__ float wave_sums[4];  // 256 threads / 64
    int lane = threadIdx.x & 63;
    int wid  = threadIdx.x >> 6;
    if (lane == 0) wave_sums[wid] = sum;
    __syncthreads();
    if (threadIdx.x == 0) {
        float b = wave_sums[0] + wave_sums[1] + wave_sums[2] + wave_sums[3];
        atomicAdd(acc, (double)b);   // device-scope by default; one per block
    }
}

__global__ void giou_finalize_kernel(const double* __restrict__ acc,
                                     float* __restrict__ out, double inv_n) {
    if (threadIdx.x == 0 && blockIdx.x == 0)
        *out = (float)(*acc * inv_n);
}

extern "C" void kernel_launch(void* const* d_in, const int* in_sizes, int n_in,
                              void* d_out, int out_size, void* d_ws, size_t ws_size,
                              hipStream_t stream) {
    const float4* pred = (const float4*)d_in[0];
    const float4* targ = (const float4*)d_in[1];
    float* out = (float*)d_out;
    double* acc = (double*)d_ws;
    int n = in_sizes[0] / 4;   // 4,000,000 boxes

    giou_zero_kernel<<<1, 64, 0, stream>>>(acc);

    const int block = 256;
    int grid = 4096;  // grid-stride: ~4 float4 pairs per thread, saturates 256 CUs
    giou_main_kernel<<<grid, block, 0, stream>>>(pred, targ, acc, n);

    giou_finalize_kernel<<<1, 64, 0, stream>>>(acc, out, 1.0 / (double)n);
}

// Round 2
// 142.276 us; speedup vs baseline: 1.1802x; 1.1802x over previous
//
#include <hip/hip_runtime.h>

// GIoU loss, N=4M boxes, [N,4] f32 -> one float4 per box (coalesced 16B/lane).
// Memory-bound: 128 MB read/launch (~half served by Infinity Cache after the
// harness restore). R1 showed 67us @ 950 GB/s HBM, VALUBusy 10%: latency-bound
// (12 VGPR, single iteration in flight) + 4096 same-address fp64 atomics.
// R2: 4x manual unroll (8 float4 in flight/thread), per-block partial slots in
// d_ws (no atomics, no init kernel), one-block finalize.

#define TPB     256
#define BLOCKS  976                      // stride*4 = 3,997,696; tail = 2,304
#define STRIDE  (BLOCKS * TPB)           // 249,856

__device__ __forceinline__ float giou_term(float4 p, float4 t) {
    float area_p = (p.z - p.x) * (p.w - p.y);
    float area_t = (t.z - t.x) * (t.w - t.y);
    float iw = fmaxf(fminf(p.z, t.z) - fmaxf(p.x, t.x), 0.0f);
    float ih = fmaxf(fminf(p.w, t.w) - fmaxf(p.y, t.y), 0.0f);
    float inter = iw * ih;
    float uni   = area_p + area_t - inter;
    float iou   = inter / uni;
    float cw = fmaxf(p.z, t.z) - fminf(p.x, t.x);
    float ch = fmaxf(p.w, t.w) - fminf(p.y, t.y);
    float area_c = cw * ch;
    return 1.0f - (iou - (area_c - uni) / area_c);
}

__global__ __launch_bounds__(TPB) void giou_main_kernel(
        const float4* __restrict__ pred,
        const float4* __restrict__ targ,
        float* __restrict__ partials,
        int n) {
    const int tid = blockIdx.x * TPB + threadIdx.x;
    float sum = 0.0f;

    int i = tid;
    // main unrolled-by-4 loop: all 8 loads issued before any consumption
    for (; i + 3 * STRIDE < n; i += 4 * STRIDE) {
        float4 p0 = pred[i];
        float4 p1 = pred[i + STRIDE];
        float4 p2 = pred[i + 2 * STRIDE];
        float4 p3 = pred[i + 3 * STRIDE];
        float4 t0 = targ[i];
        float4 t1 = targ[i + STRIDE];
        float4 t2 = targ[i + 2 * STRIDE];
        float4 t3 = targ[i + 3 * STRIDE];
        sum += giou_term(p0, t0);
        sum += giou_term(p1, t1);
        sum += giou_term(p2, t2);
        sum += giou_term(p3, t3);
    }
    // tail: only 2304 elements -> first 2304 threads do one each
    for (; i < n; i += STRIDE)
        sum += giou_term(pred[i], targ[i]);

    // wave reduce (wave = 64)
    #pragma unroll
    for (int off = 32; off > 0; off >>= 1)
        sum += __shfl_down(sum, off, 64);

    __shared__ float wave_sums[TPB / 64];
    int lane = threadIdx.x & 63;
    int wid  = threadIdx.x >> 6;
    if (lane == 0) wave_sums[wid] = sum;
    __syncthreads();
    if (threadIdx.x == 0) {
        partials[blockIdx.x] = wave_sums[0] + wave_sums[1]
                             + wave_sums[2] + wave_sums[3];
    }
}

__global__ __launch_bounds__(TPB) void giou_finalize_kernel(
        const float* __restrict__ partials,
        float* __restrict__ out, double inv_n) {
    // one block: 256 threads cover 976 partials (4 each), double accumulate
    double s = 0.0;
    for (int i = threadIdx.x; i < BLOCKS; i += TPB)
        s += (double)partials[i];
    #pragma unroll
    for (int off = 32; off > 0; off >>= 1)
        s += __shfl_down(s, off, 64);
    __shared__ double wave_sums[TPB / 64];
    int lane = threadIdx.x & 63;
    int wid  = threadIdx.x >> 6;
    if (lane == 0) wave_sums[wid] = s;
    __syncthreads();
    if (threadIdx.x == 0) {
        double tot = wave_sums[0] + wave_sums[1] + wave_sums[2] + wave_sums[3];
        *out = (float)(tot * inv_n);
    }
}

extern "C" void kernel_launch(void* const* d_in, const int* in_sizes, int n_in,
                              void* d_out, int out_size, void* d_ws, size_t ws_size,
                              hipStream_t stream) {
    const float4* pred = (const float4*)d_in[0];
    const float4* targ = (const float4*)d_in[1];
    float* out      = (float*)d_out;
    float* partials = (float*)d_ws;       // BLOCKS floats; every slot written
    int n = in_sizes[0] / 4;              // 4,000,000 boxes

    giou_main_kernel<<<BLOCKS, TPB, 0, stream>>>(pred, targ, partials, n);
    giou_finalize_kernel<<<1, TPB, 0, stream>>>(partials, out, 1.0 / (double)n);
}